// Round 7
// baseline (858.517 us; speedup 1.0000x reference)
//
#include <hip/hip_runtime.h>
#include <stdint.h>

typedef __attribute__((ext_vector_type(8))) _Float16 half8;
typedef __attribute__((ext_vector_type(2))) _Float16 half2v;
typedef __attribute__((ext_vector_type(4))) float floatx4;
typedef __attribute__((ext_vector_type(4))) uint32_t uint4v;

#define KDIM 4096
#define NDIM 11008
#define NKT 64

#define GLOAD_LDS16(gsrc, ldst)                                                        \
  __builtin_amdgcn_global_load_lds(                                                    \
      (const __attribute__((address_space(1))) void*)(gsrc),                           \
      (__attribute__((address_space(3))) void*)(ldst), 16, 0, 0)

static __device__ __forceinline__ uint32_t pkrtz(float a, float b) {
  auto h = __builtin_amdgcn_cvt_pkrtz(a, b);  // exact: values fp16-representable
  return __builtin_bit_cast(uint32_t, h);
}

// int32 of 8 nibbles -> half8 of (q-8)/7.5*s in k-order; exact (q-8) via 0x6400 trick.
static __device__ __forceinline__ half8 dq8(uint32_t q, half2v ssv) {
  half2v off; off[0] = (_Float16)(-1032.0f); off[1] = (_Float16)(-1032.0f);
  const uint32_t a0 = (q & 0x000F000Fu) | 0x64006400u;
  const uint32_t a1 = ((q >> 4) & 0x000F000Fu) | 0x64006400u;
  const uint32_t a2 = ((q >> 8) & 0x000F000Fu) | 0x64006400u;
  const uint32_t a3 = ((q >> 12) & 0x000F000Fu) | 0x64006400u;
  const uint32_t p0 = __builtin_amdgcn_perm(a1, a0, 0x05040100u);
  const uint32_t p1 = __builtin_amdgcn_perm(a3, a2, 0x05040100u);
  const uint32_t p2 = __builtin_amdgcn_perm(a1, a0, 0x07060302u);
  const uint32_t p3 = __builtin_amdgcn_perm(a3, a2, 0x07060302u);
  uint4v u;
  u[0] = __builtin_bit_cast(uint32_t, (__builtin_bit_cast(half2v, p0) + off) * ssv);
  u[1] = __builtin_bit_cast(uint32_t, (__builtin_bit_cast(half2v, p1) + off) * ssv);
  u[2] = __builtin_bit_cast(uint32_t, (__builtin_bit_cast(half2v, p2) + off) * ssv);
  u[3] = __builtin_bit_cast(uint32_t, (__builtin_bit_cast(half2v, p3) + off) * ssv);
  return __builtin_bit_cast(half8, u);
}

// ---------------- prepass: fp32 -> fp16 copy of X into workspace ----------------
__global__ __launch_bounds__(256)
void l4b_prep(const float* __restrict__ in, _Float16* __restrict__ out, int n8) {
  int i = blockIdx.x * 256 + threadIdx.x;
  if (i < n8) {
    floatx4 v0 = ((const floatx4*)in)[2 * i];
    floatx4 v1 = ((const floatx4*)in)[2 * i + 1];
    uint4v u;
    u[0] = pkrtz(v0[0], v0[1]); u[1] = pkrtz(v0[2], v0[3]);
    u[2] = pkrtz(v1[0], v1[1]); u[3] = pkrtz(v1[2], v1[3]);
    ((uint4v*)out)[i] = u;
  }
}

// ---------------- main: 256x256, A via gload_lds DMA, counted-vmcnt pipeline ----------------
__global__ __launch_bounds__(512, 2)
void l4b_main(const _Float16* __restrict__ XH,
              const int* __restrict__ PW,
              const float* __restrict__ SC,
              float* __restrict__ OUT)
{
  // Row = 64 halves = 128B = 8 x 16B slots; phys slot p holds logical slot p ^ (row&7).
  __shared__ alignas(16) _Float16 la[2][256 * 64];  // 64 KB
  __shared__ alignas(16) _Float16 lb[2][256 * 64];  // 64 KB

  const int tid  = threadIdx.x;
  const int lane = tid & 63;
  const int wave = tid >> 6;

  // XCD-aware bijective swizzle (grid = 1376 = 8*172)
  const int cpx = (int)gridDim.x >> 3;
  const int wg  = ((int)blockIdx.x & 7) * cpx + ((int)blockIdx.x >> 3);
  const int by  = wg / 43;
  const int bx  = wg - by * 43;
  const int64_t brow = (int64_t)by * 256;
  const int     bcol = bx * 256;

  // 2M x 4N wave grid, wave tile 128x64
  const int wr = (wave >> 2) * 128;
  const int wc = (wave & 3) * 64;
  const int fr = lane & 15;
  const int fq = lane >> 4;

  floatx4 acc[8][4];
#pragma unroll
  for (int i = 0; i < 8; ++i)
#pragma unroll
    for (int j = 0; j < 4; ++j) acc[i][j] = (floatx4)(0.0f);

  // A DMA: per wave 4 insts; inst g8 writes rows wave*32+g8*8 .. +7 (1 KB linear dest)
  const int arow8 = lane >> 3;
  const int aslot = (lane & 7) ^ arow8;  // pre-swizzled source slot
  const _Float16* const asrc0 =
      XH + (brow + wave * 32 + arow8) * (int64_t)KDIM + aslot * 8;

  // B staging: thread -> (col = tid&255, kq = tid>>8); 4 int32 + 1 scale per kt
  const int bc  = tid & 255;
  const int bkq = tid >> 8;
  const int*   const pwcol = PW + bcol + bc;
  const float* const sccol = SC + bcol + bc;

  int   rw0[4], rw1[4];
  float rs0, rs1;

#define DMA_A(t, dst)                                                      \
  do {                                                                     \
    _Pragma("unroll") for (int g8 = 0; g8 < 4; ++g8)                       \
        GLOAD_LDS16(asrc0 + (int64_t)g8 * 8 * KDIM + (t) * 64,             \
                    &(dst)[(wave * 32 + g8 * 8) * 64]);                    \
  } while (0)

#define LOADB(t, rwv, rs)                                                  \
  do {                                                                     \
    const int* pp = pwcol + ((t) * 8 + bkq) * NDIM;                        \
    _Pragma("unroll") for (int j_ = 0; j_ < 4; ++j_)                       \
        rwv[j_] = pp[j_ * 2 * NDIM];                                       \
    rs = sccol[(int64_t)((t) >> 1) * NDIM];                                \
  } while (0)

#define WRITE_B(dst, rwv, rs)                                              \
  do {                                                                     \
    const _Float16 ss = (_Float16)((rs) * (1.0f / 7.5f));                  \
    half2v sv; sv[0] = ss; sv[1] = ss;                                     \
    _Pragma("unroll") for (int j_ = 0; j_ < 4; ++j_) {                     \
      half8 v = dq8((uint32_t)rwv[j_], sv);                                \
      const int kp = bkq + 2 * j_;                                         \
      *(half8*)&(dst)[bc * 64 + ((kp ^ (bc & 7)) * 8)] = v;                \
    }                                                                      \
  } while (0)

#define READ_B4(src, ksl)                                                  \
  _Pragma("unroll") for (int fn_ = 0; fn_ < 4; ++fn_) {                    \
    const int n_ = wc + fn_ * 16 + fr;                                     \
    bfr[fn_] = *(const half8*)&(src)[n_ * 64 + (((ksl) ^ (n_ & 7)) * 8)];  \
  }

#define READ_A4(src, fm0, ksl)                                             \
  _Pragma("unroll") for (int fm_ = 0; fm_ < 4; ++fm_) {                    \
    const int m_ = wr + ((fm0) + fm_) * 16 + fr;                           \
    af[fm_] = *(const half8*)&(src)[m_ * 64 + (((ksl) ^ (m_ & 7)) * 8)];   \
  }

#define MFMA16(fm0)                                                        \
  __builtin_amdgcn_s_setprio(1);                                           \
  _Pragma("unroll") for (int fm_ = 0; fm_ < 4; ++fm_)                      \
  _Pragma("unroll") for (int fn_ = 0; fn_ < 4; ++fn_)                      \
      acc[(fm0) + fm_][fn_] = __builtin_amdgcn_mfma_f32_16x16x32_f16(      \
          af[fm_], bfr[fn_], acc[(fm0) + fm_][fn_], 0, 0, 0);              \
  __builtin_amdgcn_s_setprio(0);

#define PH_BAR()                                                           \
  do {                                                                     \
    __builtin_amdgcn_sched_barrier(0);                                     \
    __builtin_amdgcn_s_barrier();                                          \
    __builtin_amdgcn_sched_barrier(0);                                     \
  } while (0)

  // One K-step. Consumes rwc/rsc (B data for tile KT+1, loaded one kt ago);
  // loads rwn/rsn <- B(KT+2) and issues DMA(KT+2) into laP (just-vacated buffer).
#define KT_BODY(laP, lbP, lbN, rwc, rsc, rwn, rsn, KT, STG, LDF)           \
  do {                                                                     \
    half8 af[4], bfr[4];                                                   \
    /* P1 */                                                               \
    READ_B4(lbP, fq);                                                      \
    READ_A4(laP, 0, fq);                                                   \
    PH_BAR();                                                              \
    MFMA16(0);                                                             \
    PH_BAR();                                                              \
    /* P2 */                                                               \
    READ_A4(laP, 4, fq);                                                   \
    PH_BAR();                                                              \
    MFMA16(4);                                                             \
    PH_BAR();                                                              \
    /* P3: stage B tile KT+1 */                                            \
    READ_B4(lbP, 4 + fq);                                                  \
    READ_A4(laP, 0, 4 + fq);                                               \
    if (STG) WRITE_B(lbN, rwc, rsc);                                       \
    PH_BAR();                                                              \
    MFMA16(0);                                                             \
    PH_BAR();                                                              \
    /* P4: retire all LDS reads of laP, then (post-barrier) reuse it */    \
    READ_A4(laP, 4, 4 + fq);                                               \
    asm volatile("s_waitcnt lgkmcnt(0)" ::: "memory");                     \
    __builtin_amdgcn_sched_barrier(0);                                     \
    __builtin_amdgcn_s_barrier();  /* all waves' laP reads retired */      \
    __builtin_amdgcn_sched_barrier(0);                                     \
    if (LDF) {                                                             \
      LOADB(KT + 2, rwn, rsn);  /* 5 VMEM */                               \
      DMA_A(KT + 2, laP);       /* 4 VMEM */                               \
    }                                                                      \
    __builtin_amdgcn_sched_barrier(0);                                     \
    MFMA16(4);                                                             \
    __builtin_amdgcn_sched_barrier(0);                                     \
    if (LDF) { asm volatile("s_waitcnt vmcnt(9)" ::: "memory"); }          \
    else     { asm volatile("s_waitcnt vmcnt(0)" ::: "memory"); }          \
    __builtin_amdgcn_sched_barrier(0);                                     \
    __builtin_amdgcn_s_barrier();  /* end of kt: tile KT+1 ready */        \
    __builtin_amdgcn_sched_barrier(0);                                     \
  } while (0)

  // ---- prologue: stage tile 0; tiles 0,1 A-DMA + tile-1 B regs in flight ----
  LOADB(0, rw0, rs0);
  DMA_A(0, la[0]);
  WRITE_B(lb[0], rw0, rs0);     // compiler-counted vmcnt wait on rw0
  LOADB(1, rw1, rs1);           // consumed at kt0 P3
  DMA_A(1, la[1]);
  asm volatile("s_waitcnt vmcnt(9)" ::: "memory");  // DMA(0) complete
  asm volatile("s_waitcnt lgkmcnt(0)" ::: "memory");
  __builtin_amdgcn_s_barrier();
  __builtin_amdgcn_sched_barrier(0);

  // kt 0..61 full pipeline; even kt consumes rw1, loads rw0; odd the reverse
  for (int g = 0; g < 31; ++g) {
    const int kt = 2 * g;
    KT_BODY(la[0], lb[0], lb[1], rw1, rs1, rw0, rs0, kt,     true, true);
    KT_BODY(la[1], lb[1], lb[0], rw0, rs0, rw1, rs1, kt + 1, true, true);
  }
  // tail
  KT_BODY(la[0], lb[0], lb[1], rw1, rs1, rw0, rs0, 62, true,  false);
  KT_BODY(la[1], lb[1], lb[0], rw0, rs0, rw1, rs1, 63, false, false);

  // ---- epilogue: C/D map col=lane&15, row=(lane>>4)*4+reg; fp32 out ----
#pragma unroll
  for (int fm = 0; fm < 8; ++fm)
#pragma unroll
    for (int fn = 0; fn < 4; ++fn)
#pragma unroll
      for (int r = 0; r < 4; ++r) {
        const int64_t row = brow + wr + fm * 16 + fq * 4 + r;
        const int     col = bcol + wc + fn * 16 + fr;
        OUT[row * NDIM + col] = acc[fm][fn][r];
      }
}

// ---------------- fallback (fp32-input path, proven r3): only if ws too small ----------------
__global__ __launch_bounds__(512, 2)
void l4b_fb(const float* __restrict__ X, const int* __restrict__ PW,
            const float* __restrict__ SC, float* __restrict__ OUT)
{
  __shared__ alignas(16) _Float16 fla[2][256 * 64];
  __shared__ alignas(16) _Float16 flb[2][256 * 64];

  const int tid  = threadIdx.x;
  const int lane = tid & 63;
  const int wave = tid >> 6;

  const int cpx = (int)gridDim.x >> 3;
  const int wg  = ((int)blockIdx.x & 7) * cpx + ((int)blockIdx.x >> 3);
  const int by  = wg / 43;
  const int bx  = wg - by * 43;
  const int64_t brow = (int64_t)by * 256;
  const int     bcol = bx * 256;

  const int wr = (wave >> 2) * 128;
  const int wc = (wave & 3) * 64;
  const int fr = lane & 15;
  const int fq = lane >> 4;

  floatx4 acc[8][4];
#pragma unroll
  for (int i = 0; i < 8; ++i)
#pragma unroll
    for (int j = 0; j < 4; ++j) acc[i][j] = (floatx4)(0.0f);

  const int ar = tid >> 1;
  const int ah = tid & 1;
  const float* const aptr = X + (brow + ar) * (int64_t)KDIM + ah * 32;
  const int bc  = tid & 255;
  const int bkq = tid >> 8;
  const int*   const pwcol = PW + bcol + bc;
  const float* const sccol = SC + bcol + bc;

  floatx4 ra[8];
  int     rwf[4];
  float   rsc;

#define F_LOAD_A(t)                                                        \
  do {                                                                     \
    const float* ap = aptr + (t) * 64;                                     \
    _Pragma("unroll") for (int i_ = 0; i_ < 8; ++i_)                       \
        ra[i_] = *(const floatx4*)(ap + i_ * 4);                           \
  } while (0)

#define F_LOAD_B(t)                                                        \
  do {                                                                     \
    const int* pp = pwcol + ((t) * 8 + bkq) * NDIM;                        \
    _Pragma("unroll") for (int j_ = 0; j_ < 4; ++j_)                       \
        rwf[j_] = pp[j_ * 2 * NDIM];                                       \
    rsc = sccol[(int64_t)((t) >> 1) * NDIM];                               \
  } while (0)

#define F_WRITE_A(dst)                                                     \
  do {                                                                     \
    _Pragma("unroll") for (int i2 = 0; i2 < 4; ++i2) {                     \
      uint4v u;                                                            \
      u[0] = pkrtz(ra[2 * i2][0], ra[2 * i2][1]);                          \
      u[1] = pkrtz(ra[2 * i2][2], ra[2 * i2][3]);                          \
      u[2] = pkrtz(ra[2 * i2 + 1][0], ra[2 * i2 + 1][1]);                  \
      u[3] = pkrtz(ra[2 * i2 + 1][2], ra[2 * i2 + 1][3]);                  \
      const int s_ = ah * 4 + i2;                                          \
      *(half8*)&(dst)[ar * 64 + ((s_ ^ (ar & 7)) * 8)] =                   \
          __builtin_bit_cast(half8, u);                                    \
    }                                                                      \
  } while (0)

#define F_WRITE_B(dst)                                                     \
  do {                                                                     \
    const _Float16 ssf = (_Float16)(rsc * (1.0f / 7.5f));                  \
    half2v sv; sv[0] = ssf; sv[1] = ssf;                                   \
    _Pragma("unroll") for (int j_ = 0; j_ < 4; ++j_) {                     \
      half8 v = dq8((uint32_t)rwf[j_], sv);                                \
      const int kp = bkq + 2 * j_;                                         \
      *(half8*)&(dst)[bc * 64 + ((kp ^ (bc & 7)) * 8)] = v;                \
    }                                                                      \
  } while (0)

#define F_MFMA16(fm0)                                                      \
  __builtin_amdgcn_s_barrier();                                            \
  asm volatile("s_waitcnt lgkmcnt(0)" ::: "memory");                       \
  __builtin_amdgcn_sched_barrier(0);                                       \
  __builtin_amdgcn_s_setprio(1);                                           \
  _Pragma("unroll") for (int fm_ = 0; fm_ < 4; ++fm_)                      \
  _Pragma("unroll") for (int fn_ = 0; fn_ < 4; ++fn_)                      \
      acc[(fm0) + fm_][fn_] = __builtin_amdgcn_mfma_f32_16x16x32_f16(      \
          af[fm_], bfr[fn_], acc[(fm0) + fm_][fn_], 0, 0, 0);              \
  __builtin_amdgcn_s_setprio(0);                                           \
  __builtin_amdgcn_sched_barrier(0);                                       \
  __builtin_amdgcn_s_barrier();                                            \
  __builtin_amdgcn_sched_barrier(0);

  F_LOAD_A(0); F_LOAD_B(0);
  F_WRITE_A(fla[0]); F_WRITE_B(flb[0]);
  F_LOAD_A(1); F_LOAD_B(1);
  asm volatile("s_waitcnt lgkmcnt(0)" ::: "memory");
  __builtin_amdgcn_s_barrier();
  __builtin_amdgcn_sched_barrier(0);

  for (int kt = 0; kt < NKT; ++kt) {
    const int buf = kt & 1;
    const _Float16* lap = fla[buf];
    const _Float16* lbp = flb[buf];
    _Float16* const lan = fla[buf ^ 1];
    _Float16* const lbn = flb[buf ^ 1];
    const bool haveW = (kt + 1 < NKT);
    const bool haveL = (kt + 2 < NKT);

    half8 bfr[4], af[4];

#pragma unroll
    for (int fn_ = 0; fn_ < 4; ++fn_) {
      const int n_ = wc + fn_ * 16 + fr;
      bfr[fn_] = *(const half8*)&lbp[n_ * 64 + ((fq ^ (n_ & 7)) * 8)];
    }
#pragma unroll
    for (int fm_ = 0; fm_ < 4; ++fm_) {
      const int m_ = wr + fm_ * 16 + fr;
      af[fm_] = *(const half8*)&lap[m_ * 64 + ((fq ^ (m_ & 7)) * 8)];
    }
    if (haveW) F_WRITE_A(lan);
    F_MFMA16(0);

#pragma unroll
    for (int fm_ = 0; fm_ < 4; ++fm_) {
      const int m_ = wr + (4 + fm_) * 16 + fr;
      af[fm_] = *(const half8*)&lap[m_ * 64 + ((fq ^ (m_ & 7)) * 8)];
    }
    if (haveL) F_LOAD_A(kt + 2);
    F_MFMA16(4);

#pragma unroll
    for (int fn_ = 0; fn_ < 4; ++fn_) {
      const int n_ = wc + fn_ * 16 + fr;
      bfr[fn_] = *(const half8*)&lbp[n_ * 64 + (((4 + fq) ^ (n_ & 7)) * 8)];
    }
#pragma unroll
    for (int fm_ = 0; fm_ < 4; ++fm_) {
      const int m_ = wr + fm_ * 16 + fr;
      af[fm_] = *(const half8*)&lap[m_ * 64 + (((4 + fq) ^ (m_ & 7)) * 8)];
    }
    if (haveW) F_WRITE_B(lbn);
    F_MFMA16(0);

#pragma unroll
    for (int fm_ = 0; fm_ < 4; ++fm_) {
      const int m_ = wr + (4 + fm_) * 16 + fr;
      af[fm_] = *(const half8*)&lap[m_ * 64 + (((4 + fq) ^ (m_ & 7)) * 8)];
    }
    if (haveL) F_LOAD_B(kt + 2);
    F_MFMA16(4);
  }

#pragma unroll
  for (int fm = 0; fm < 8; ++fm)
#pragma unroll
    for (int fn = 0; fn < 4; ++fn)
#pragma unroll
      for (int r = 0; r < 4; ++r) {
        const int64_t row = brow + wr + fm * 16 + fq * 4 + r;
        const int     col = bcol + wc + fn * 16 + fr;
        OUT[row * NDIM + col] = acc[fm][fn][r];
      }
}

extern "C" void kernel_launch(void* const* d_in, const int* in_sizes, int n_in,
                              void* d_out, int out_size, void* d_ws, size_t ws_size,
                              hipStream_t stream) {
  const float* X   = (const float*)d_in[0];
  const int*   PW  = (const int*)d_in[1];
  const float* SC  = (const float*)d_in[2];
  float*       OUT = (float*)d_out;

  const int    M     = in_sizes[0] / KDIM;       // 8192
  const size_t needH = (size_t)in_sizes[0] * 2;  // fp16 copy of X
  const int    grid  = (M / 256) * (NDIM / 256); // 32 * 43 = 1376

  if (ws_size >= needH && (M % 256) == 0) {
    _Float16* XH = (_Float16*)d_ws;
    const int n8 = in_sizes[0] / 8;
    l4b_prep<<<(n8 + 255) / 256, 256, 0, stream>>>(X, XH, n8);
    l4b_main<<<grid, 512, 0, stream>>>(XH, PW, SC, OUT);
  } else {
    l4b_fb<<<grid, 512, 0, stream>>>(X, PW, SC, OUT);
  }
}